// Round 5
// baseline (423.801 us; speedup 1.0000x reference)
//
#include <hip/hip_runtime.h>
#include <hip/hip_bf16.h>
#include <math.h>

#define DF 128
#define NC 40
#define PC 20            // classes per plane (2 planes: 40 B rows -> 4 MB/plane, fits one XCD L2)
#define RB 8             // bucket = node >> 8 (256 nodes/bucket)
#define RSZ 256
#define CHUNK 4096       // edges per binning block
#define CAP 12288        // slab capacity per bucket

typedef float f32x4 __attribute__((ext_vector_type(4)));

__device__ __forceinline__ float bf2f(unsigned short h) {
  unsigned int u = ((unsigned int)h) << 16;
  union { unsigned int u; float f; } c; c.u = u; return c.f;
}
__device__ __forceinline__ unsigned short f2bf(float x) {  // round-to-nearest-even
  union { float f; unsigned int u; } c; c.f = x;
  unsigned int u = c.u;
  return (unsigned short)((u + 0x7fffu + ((u >> 16) & 1u)) >> 16);
}

// ---------- pass B: bin edges into per-bucket slab, count totals ----------
__global__ __launch_bounds__(512) void k_binB(
    const int* __restrict__ row, const int* __restrict__ col,
    int* __restrict__ cnt, unsigned int* __restrict__ slab, int E, int NB) {
  __shared__ int colS[CHUNK];   // 16 KB
  __shared__ int hist[512];
  __shared__ int cursor[512];
  int t = threadIdx.x;
  if (t < NB) hist[t] = 0;
  int s = blockIdx.x * CHUNK, e = min(E, s + CHUNK), n = e - s;
  for (int i = t; i < n; i += 512) colS[i] = col[s + i];
  __syncthreads();
  for (int i = t; i < n; i += 512) atomicAdd(&hist[colS[i] >> RB], 1);
  __syncthreads();
  if (t < NB) cursor[t] = hist[t] ? atomicAdd(&cnt[t], hist[t]) : 0;
  __syncthreads();
  for (int i = t; i < n; i += 512) {
    int c = colS[i];
    int b = c >> RB;
    int p = atomicAdd(&cursor[b], 1);
    slab[(size_t)b * CAP + p] = ((unsigned int)row[s + i] << RB) | (unsigned int)(c & (RSZ - 1));
  }
}

// ---------- pass C: per-bucket CSR finalize + dinv (bucket base computed inline) ----------
__global__ __launch_bounds__(512) void k_binC(
    const unsigned int* __restrict__ slab, const int* __restrict__ cnt,
    int* __restrict__ off, int* __restrict__ eidx, float* __restrict__ dinv,
    int N, int NB, int E) {
  __shared__ int redS[512];
  __shared__ int hist[RSZ];
  __shared__ int sc[RSZ];
  __shared__ int cur[RSZ];
  int b = blockIdx.x;
  int t = threadIdx.x;
  // exclusive prefix of cnt over buckets < b (replaces the single-block scan kernel)
  redS[t] = (t < NB && t < b) ? cnt[t] : 0;
  if (t < RSZ) hist[t] = 0;
  __syncthreads();
  for (int o = 256; o > 0; o >>= 1) {
    if (t < o) redS[t] += redS[t + o];
    __syncthreads();
  }
  int cb = redS[0];
  int cnt_b = cnt[b];
  if (b == 0 && t == 0) off[N] = E;
  const unsigned int* src = slab + (size_t)b * CAP;
  for (int i = t; i < cnt_b; i += 512) atomicAdd(&hist[src[i] & (RSZ - 1)], 1);
  __syncthreads();
  int v = (t < RSZ) ? hist[t] : 0;
  if (t < RSZ) sc[t] = v;
  __syncthreads();
  for (int o = 1; o < RSZ; o <<= 1) {
    int u = (t < RSZ && t >= o) ? sc[t - o] : 0;
    __syncthreads();
    if (t < RSZ) sc[t] += u;
    __syncthreads();
  }
  if (t < RSZ) {
    int pos = cb + sc[t] - v;
    int node = (b << RB) + t;
    if (node < N) {
      off[node] = pos;
      dinv[node] = rsqrtf((float)v + 2.0f);  // degree + 2 self-loops
    }
    cur[t] = pos;
  }
  __syncthreads();
  for (int i = t; i < cnt_b; i += 512) {
    unsigned int en = src[i];
    int p = atomicAdd(&cur[en & (RSZ - 1)], 1);
    eidx[p] = (int)(en >> RB);
  }
}

// ---------- projection first: g0 planes = bf16( dinv[n] * (x[n] @ W^T) ) ----------
// plane p (p=0,1) holds classes [p*20, p*20+20) as 40 B rows: base = g0 + p*N*PC ushorts
__global__ __launch_bounds__(128) void k_xw_scale(
    const float* __restrict__ x, const float* __restrict__ W,
    const float* __restrict__ dinv, unsigned short* __restrict__ g0, int N) {
  __shared__ float4 Ws[NC * (DF / 4)];  // 20 KB
  for (int i = threadIdx.x; i < NC * (DF / 4); i += blockDim.x)
    Ws[i] = ((const float4*)W)[i];
  __syncthreads();
  int node = blockIdx.x * blockDim.x + threadIdx.x;
  if (node >= N) return;
  float acc[NC];
#pragma unroll
  for (int c = 0; c < NC; ++c) acc[c] = 0.f;
  const float4* xr = (const float4*)(x + (size_t)node * DF);
#pragma unroll 1
  for (int ch = 0; ch < 8; ++ch) {
    float4 v0 = xr[ch * 4 + 0];
    float4 v1 = xr[ch * 4 + 1];
    float4 v2 = xr[ch * 4 + 2];
    float4 v3 = xr[ch * 4 + 3];
#pragma unroll
    for (int c = 0; c < NC; ++c) {
      float4 w0 = Ws[c * (DF / 4) + ch * 4 + 0];
      float4 w1 = Ws[c * (DF / 4) + ch * 4 + 1];
      float4 w2 = Ws[c * (DF / 4) + ch * 4 + 2];
      float4 w3 = Ws[c * (DF / 4) + ch * 4 + 3];
      acc[c] += (v0.x * w0.x + v0.y * w0.y + v0.z * w0.z + v0.w * w0.w) +
                (v1.x * w1.x + v1.y * w1.y + v1.z * w1.z + v1.w * w1.w) +
                (v2.x * w2.x + v2.y * w2.y + v2.z * w2.z + v2.w * w2.w) +
                (v3.x * w3.x + v3.y * w3.y + v3.z * w3.z + v3.w * w3.w);
    }
  }
  float di = dinv[node];
  unsigned int pk[NC / 2];
#pragma unroll
  for (int c2 = 0; c2 < NC / 2; ++c2) {
    unsigned int lo = f2bf(di * acc[c2 * 2 + 0]);
    unsigned int hi = f2bf(di * acc[c2 * 2 + 1]);
    pk[c2] = lo | (hi << 16);
  }
  uint2* p0 = (uint2*)g0 + (size_t)node * 5;
  uint2* p1 = (uint2*)g0 + (size_t)N * 5 + (size_t)node * 5;
#pragma unroll
  for (int q = 0; q < 5; ++q) {
    p0[q] = make_uint2(pk[2 * q], pk[2 * q + 1]);
    p1[q] = make_uint2(pk[10 + 2 * q], pk[10 + 2 * q + 1]);
  }
}

// ---------- hop kernel: classes-as-lanes. one wave = 3 nodes x 20 lanes ----------
// Lane owns ONE class of one node: the class sum lives in a single register ->
// no cross-lane reduce at all, no masks in the main loop (full 8-edge
// iterations with immediate-offset eidx loads; <=7-edge serial tail).
// Gather: 20 lanes x 2 B = 40 B contiguous per row (1-2 L2 line requests).
// Block->plane assignment rides blockIdx%8 so XCDs 0-3 only touch plane 0,
// XCDs 4-7 only plane 1 (round-robin dispatch heuristic; correctness-safe).
template<int FINAL>
__global__ __launch_bounds__(256) void k_hop(
    const int* __restrict__ off, const int* __restrict__ eidx,
    const float* __restrict__ dinv, const unsigned short* __restrict__ gin,
    unsigned short* __restrict__ gout, float* __restrict__ logits,
    const float* __restrict__ bias, int N, int NBH) {
  int bid = blockIdx.x;
  int slot8 = bid & 7;
  int half = slot8 >> 2;                       // plane id 0/1
  int nbi = ((bid >> 3) << 2) + (slot8 & 3);   // node-block index within plane
  if (nbi >= NBH) return;
  int lane = threadIdx.x & 63;
  int wv = threadIdx.x >> 6;
  int g = lane / 20;                           // node group 0..2 (g==3: lanes 60-63 idle)
  int cls = lane - g * 20;                     // class within plane
  int node = nbi * 12 + wv * 3 + g;            // 12 nodes per block
  bool act = (g < 3) && (node < N);
  int nc = act ? node : 0;
  int s = off[nc];                             // uniform within 20-lane group (broadcast)
  int e = off[nc + 1];
  if (!act) e = s;
  float di = dinv[nc];
  const unsigned short* plane = gin + (size_t)half * ((size_t)N * PC);
  float acc = act ? 2.0f * bf2f(plane[(size_t)nc * PC + cls]) : 0.f;  // double self-loop
  int i = s;
  for (; i + 8 <= e; i += 8) {                 // full shots: 8 gathers in flight, no masks
    int r0 = __builtin_nontemporal_load(eidx + i + 0);
    int r1 = __builtin_nontemporal_load(eidx + i + 1);
    int r2 = __builtin_nontemporal_load(eidx + i + 2);
    int r3 = __builtin_nontemporal_load(eidx + i + 3);
    int r4 = __builtin_nontemporal_load(eidx + i + 4);
    int r5 = __builtin_nontemporal_load(eidx + i + 5);
    int r6 = __builtin_nontemporal_load(eidx + i + 6);
    int r7 = __builtin_nontemporal_load(eidx + i + 7);
    unsigned short v0 = plane[(size_t)r0 * PC + cls];
    unsigned short v1 = plane[(size_t)r1 * PC + cls];
    unsigned short v2 = plane[(size_t)r2 * PC + cls];
    unsigned short v3 = plane[(size_t)r3 * PC + cls];
    unsigned short v4 = plane[(size_t)r4 * PC + cls];
    unsigned short v5 = plane[(size_t)r5 * PC + cls];
    unsigned short v6 = plane[(size_t)r6 * PC + cls];
    unsigned short v7 = plane[(size_t)r7 * PC + cls];
    acc += ((bf2f(v0) + bf2f(v1)) + (bf2f(v2) + bf2f(v3))) +
           ((bf2f(v4) + bf2f(v5)) + (bf2f(v6) + bf2f(v7)));
  }
  for (; i < e; ++i) {                         // tail <= 7 edges
    int r = __builtin_nontemporal_load(eidx + i);
    acc += bf2f(plane[(size_t)r * PC + cls]);
  }
  if (act) {
    if (FINAL) {
      float vlog = di * acc + bias[half * PC + cls];
      __builtin_nontemporal_store(vlog, logits + (size_t)node * NC + half * PC + cls);
    } else {
      // normal (cached) store is NOT used: keep the hot gather plane resident,
      // stream g1 out (hop<1> re-fetches it linearly — cheap)
      unsigned short pv = f2bf(di * di * acc);
      __builtin_nontemporal_store(pv,
          gout + (size_t)half * ((size_t)N * PC) + (size_t)node * PC + cls);
    }
  }
}

// ---------- epilogue: log_softmax over f32 logits ----------
__global__ __launch_bounds__(256) void k_lsm(
    const float* __restrict__ logits, float* __restrict__ out, int N) {
  int wave = (int)((blockIdx.x * (size_t)blockDim.x + threadIdx.x) >> 6);
  int lane = threadIdx.x & 63;
  if (wave >= N) return;
  bool act = lane < NC;
  float v = act ? __builtin_nontemporal_load(logits + (size_t)wave * NC + lane) : -3.0e38f;
  float m = v;
#pragma unroll
  for (int o = 32; o > 0; o >>= 1) m = fmaxf(m, __shfl_xor(m, o, 64));
  float ex = act ? expf(v - m) : 0.f;
  float ssum = ex;
#pragma unroll
  for (int o = 32; o > 0; o >>= 1) ssum += __shfl_xor(ssum, o, 64);
  float lse = m + logf(ssum);
  if (act) __builtin_nontemporal_store(v - lse, out + (size_t)wave * NC + lane);
}

extern "C" void kernel_launch(void* const* d_in, const int* in_sizes, int n_in,
                              void* d_out, int out_size, void* d_ws, size_t ws_size,
                              hipStream_t stream) {
  const float* x = (const float*)d_in[0];
  const int* ei  = (const int*)d_in[1];   // [2][E] flat: rows then cols
  const float* W = (const float*)d_in[2];
  const float* b = (const float*)d_in[3];
  // d_in[4] is K; reference fixes K=2 — hardcoded.
  float* out = (float*)d_out;

  const int N = in_sizes[0] / DF;
  const int E = in_sizes[1] / 2;
  const int NB = (N + RSZ - 1) >> RB;     // 391 buckets for N=100K (<= 512)
  const int* row  = ei;
  const int* colv = ei + E;

  char* basep = (char*)d_ws;
  auto alloc = [&](size_t bytes) {
    char* p = basep;
    basep += (bytes + 511) & ~(size_t)511;
    return p;
  };
  int*   cnt    = (int*)  alloc(((size_t)NB) * 4);
  unsigned int* slab = (unsigned int*)alloc((size_t)NB * CAP * 4);  // 19.2 MB
  int*   off    = (int*)  alloc(((size_t)N + 1) * 4);
  int*   eidx   = (int*)  alloc((size_t)E * 4);
  float* dinv   = (float*)alloc((size_t)N * 4);
  unsigned short* g0 = (unsigned short*)alloc((size_t)N * NC * 2);  // 8 MB, 2 planes
  unsigned short* g1 = (unsigned short*)alloc((size_t)N * NC * 2);
  // logits [N][NC] f32 aliases the slab: slab is dead after k_binC, and
  // NB*CAP*4 = N*192 B >= N*160 B always. Stream order guarantees safety.
  float* logits = (float*)slab;

  const int gBin = (E + CHUNK - 1) / CHUNK;

  // CSR build: slab binning, then per-bucket finalize (bucket base inline)
  hipMemsetAsync(cnt, 0, (size_t)NB * 4, stream);
  k_binB<<<gBin, 512, 0, stream>>>(row, colv, cnt, slab, E, NB);
  k_binC<<<NB, 512, 0, stream>>>(slab, cnt, off, eidx, dinv, N, NB, E);

  // project 128 -> 40 first (propagation commutes with the linear layer)
  k_xw_scale<<<(N + 127) / 128, 128, 0, stream>>>(x, W, dinv, g0, N);

  // two hops, each split into two XCD-affine class-plane passes in one grid
  const int NBH = (N + 11) / 12;        // 12 nodes per block (4 waves x 3 nodes)
  const int NBH4 = (NBH + 3) & ~3;
  const int gHop = 2 * NBH4;            // multiple of 8: clean XCD round-robin
  k_hop<0><<<gHop, 256, 0, stream>>>(off, eidx, dinv, g0, g1, nullptr, nullptr, N, NBH);
  k_hop<1><<<gHop, 256, 0, stream>>>(off, eidx, dinv, g1, nullptr, logits, b, N, NBH);

  // fused bias already applied; log_softmax epilogue
  const int gLsm = (int)(((size_t)N * 64 + 255) / 256);
  k_lsm<<<gLsm, 256, 0, stream>>>(logits, out, N);
}

// Round 6
// 363.858 us; speedup vs baseline: 1.1647x; 1.1647x over previous
//
#include <hip/hip_runtime.h>
#include <hip/hip_bf16.h>
#include <math.h>

#define DF 128
#define NC 40
#define GST 40           // g-buffer row stride in ushorts: 80 B rows
#define RB 8             // bucket = node >> 8 (256 nodes/bucket)
#define RSZ 256
#define CHUNK 4096       // edges per binning block
#define CAP 12288        // slab capacity per bucket

__device__ __forceinline__ float bf2f(unsigned short h) {
  unsigned int u = ((unsigned int)h) << 16;
  union { unsigned int u; float f; } c; c.u = u; return c.f;
}
__device__ __forceinline__ unsigned short f2bf(float x) {  // round-to-nearest-even
  union { float f; unsigned int u; } c; c.f = x;
  unsigned int u = c.u;
  return (unsigned short)((u + 0x7fffu + ((u >> 16) & 1u)) >> 16);
}
// unpack a dword holding two packed bf16 (lo = bits 0-15, hi = bits 16-31)
__device__ __forceinline__ float blo(unsigned int u) {
  union { unsigned int u; float f; } c; c.u = u << 16; return c.f;
}
__device__ __forceinline__ float bhi(unsigned int u) {
  union { unsigned int u; float f; } c; c.u = u & 0xffff0000u; return c.f;
}

// ---------- pass B: bin edges into per-bucket slab, count totals ----------
__global__ __launch_bounds__(512) void k_binB(
    const int* __restrict__ row, const int* __restrict__ col,
    int* __restrict__ cnt, unsigned int* __restrict__ slab, int E, int NB) {
  __shared__ int colS[CHUNK];   // 16 KB
  __shared__ int hist[512];
  __shared__ int cursor[512];
  int t = threadIdx.x;
  if (t < NB) hist[t] = 0;
  int s = blockIdx.x * CHUNK, e = min(E, s + CHUNK), n = e - s;
  for (int i = t; i < n; i += 512) colS[i] = col[s + i];
  __syncthreads();
  for (int i = t; i < n; i += 512) atomicAdd(&hist[colS[i] >> RB], 1);
  __syncthreads();
  if (t < NB) cursor[t] = hist[t] ? atomicAdd(&cnt[t], hist[t]) : 0;
  __syncthreads();
  for (int i = t; i < n; i += 512) {
    int c = colS[i];
    int b = c >> RB;
    int p = atomicAdd(&cursor[b], 1);
    slab[(size_t)b * CAP + p] = ((unsigned int)row[s + i] << RB) | (unsigned int)(c & (RSZ - 1));
  }
}

// ---------- pass C: per-bucket CSR finalize + dinv (bucket base computed inline) ----------
// eidx entries are PRE-SCALED to byte offsets (r * 80) for the hop kernels.
__global__ __launch_bounds__(512) void k_binC(
    const unsigned int* __restrict__ slab, const int* __restrict__ cnt,
    int* __restrict__ off, int* __restrict__ eidx, float* __restrict__ dinv,
    int N, int NB, int E) {
  __shared__ int redS[512];
  __shared__ int hist[RSZ];
  __shared__ int sc[RSZ];
  __shared__ int cur[RSZ];
  int b = blockIdx.x;
  int t = threadIdx.x;
  // exclusive prefix of cnt over buckets < b (replaces the single-block scan kernel)
  redS[t] = (t < NB && t < b) ? cnt[t] : 0;
  if (t < RSZ) hist[t] = 0;
  __syncthreads();
  for (int o = 256; o > 0; o >>= 1) {
    if (t < o) redS[t] += redS[t + o];
    __syncthreads();
  }
  int cb = redS[0];
  int cnt_b = cnt[b];
  if (b == 0 && t == 0) off[N] = E;
  const unsigned int* src = slab + (size_t)b * CAP;
  for (int i = t; i < cnt_b; i += 512) atomicAdd(&hist[src[i] & (RSZ - 1)], 1);
  __syncthreads();
  int v = (t < RSZ) ? hist[t] : 0;
  if (t < RSZ) sc[t] = v;
  __syncthreads();
  for (int o = 1; o < RSZ; o <<= 1) {
    int u = (t < RSZ && t >= o) ? sc[t - o] : 0;
    __syncthreads();
    if (t < RSZ) sc[t] += u;
    __syncthreads();
  }
  if (t < RSZ) {
    int pos = cb + sc[t] - v;
    int node = (b << RB) + t;
    if (node < N) {
      off[node] = pos;
      dinv[node] = rsqrtf((float)v + 2.0f);  // degree + 2 self-loops
    }
    cur[t] = pos;
  }
  __syncthreads();
  for (int i = t; i < cnt_b; i += 512) {
    unsigned int en = src[i];
    int p = atomicAdd(&cur[en & (RSZ - 1)], 1);
    eidx[p] = (int)((en >> RB) * (GST * 2u));   // byte offset of source row
  }
}

// ---------- projection first: g0[n] = bf16( dinv[n] * (x[n] @ W^T) ), 80 B rows ----------
__global__ __launch_bounds__(128) void k_xw_scale(
    const float* __restrict__ x, const float* __restrict__ W,
    const float* __restrict__ dinv, unsigned short* __restrict__ g0, int N) {
  __shared__ float4 Ws[NC * (DF / 4)];  // 20 KB
  for (int i = threadIdx.x; i < NC * (DF / 4); i += blockDim.x)
    Ws[i] = ((const float4*)W)[i];
  __syncthreads();
  int node = blockIdx.x * blockDim.x + threadIdx.x;
  if (node >= N) return;
  float acc[NC];
#pragma unroll
  for (int c = 0; c < NC; ++c) acc[c] = 0.f;
  const float4* xr = (const float4*)(x + (size_t)node * DF);
#pragma unroll 1
  for (int ch = 0; ch < 8; ++ch) {
    float4 v0 = xr[ch * 4 + 0];
    float4 v1 = xr[ch * 4 + 1];
    float4 v2 = xr[ch * 4 + 2];
    float4 v3 = xr[ch * 4 + 3];
#pragma unroll
    for (int c = 0; c < NC; ++c) {
      float4 w0 = Ws[c * (DF / 4) + ch * 4 + 0];
      float4 w1 = Ws[c * (DF / 4) + ch * 4 + 1];
      float4 w2 = Ws[c * (DF / 4) + ch * 4 + 2];
      float4 w3 = Ws[c * (DF / 4) + ch * 4 + 3];
      acc[c] += (v0.x * w0.x + v0.y * w0.y + v0.z * w0.z + v0.w * w0.w) +
                (v1.x * w1.x + v1.y * w1.y + v1.z * w1.z + v1.w * w1.w) +
                (v2.x * w2.x + v2.y * w2.y + v2.z * w2.z + v2.w * w2.w) +
                (v3.x * w3.x + v3.y * w3.y + v3.z * w3.z + v3.w * w3.w);
    }
  }
  float di = dinv[node];
  unsigned int pk[NC / 2];
#pragma unroll
  for (int c2 = 0; c2 < NC / 2; ++c2) {
    unsigned int lo = f2bf(di * acc[c2 * 2 + 0]);
    unsigned int hi = f2bf(di * acc[c2 * 2 + 1]);
    pk[c2] = lo | (hi << 16);
  }
  uint4* gp = (uint4*)(g0 + (size_t)node * GST);
#pragma unroll
  for (int q = 0; q < 5; ++q)
    gp[q] = make_uint4(pk[q * 4 + 0], pk[q * 4 + 1], pk[q * 4 + 2], pk[q * 4 + 3]);
}

// ---------- hop kernel: single-pass, 3 edges/gather-instruction ----------
// One wave = one node. 60 active lanes = 3 edge-slots x 20 class-lanes; each
// lane loads a uint (2 bf16 classes) -> one gather instruction covers 3 edges'
// full 80 B rows. 36-edge masked straight-line shot (12 gathers in flight,
// min-clamped indices), then masked 3-edge cleanup for deg>36 (~21% of nodes).
// eidx holds byte offsets (r*80): per-edge address is a single v_add.
// FINAL fuses bias + log_softmax and writes the output directly.
template<int FINAL>
__global__ __launch_bounds__(256) void k_hop(
    const int* __restrict__ off, const int* __restrict__ eidx,
    const float* __restrict__ dinv, const unsigned short* __restrict__ gin,
    unsigned short* __restrict__ gout, const float* __restrict__ bias,
    float* __restrict__ out, int N) {
  int wv = threadIdx.x >> 6;
  int lane = threadIdx.x & 63;
  int node = blockIdx.x * 4 + wv;
  if (node >= N) return;
  int slot = lane / 20;                 // 0..2 edge slots; lanes 60-63: slot 3 (masked)
  int cls = lane - slot * 20;           // class-pair index 0..19
  bool sact = slot < 3;
  int s = __builtin_amdgcn_readfirstlane(off[node]);
  int e = __builtin_amdgcn_readfirstlane(off[node + 1]);
  float di = dinv[node];
  const char* base = (const char*)gin;
  int clsoff = cls * 4;
  float accL, accH;
  {                                     // double self-loop (own row, 2 classes/lane)
    unsigned int v = *(const unsigned int*)(base + (size_t)node * (GST * 2) + clsoff);
    bool s0 = (slot == 0);
    accL = s0 ? 2.f * blo(v) : 0.f;
    accH = s0 ? 2.f * bhi(v) : 0.f;
  }
  int last = (e > s) ? (e - 1) : 0;     // deg-0 guard: clamp reads to eidx[0]
  int p0 = s + slot * 12;
  // 36-edge straight-line shot: 12 independent eidx loads + 12 gathers in flight
#pragma unroll
  for (int u = 0; u < 12; ++u) {
    int p = p0 + u;
    int rb = eidx[min(p, last)];        // byte offset of source row
    unsigned int v = *(const unsigned int*)(base + (unsigned)rb + clsoff);
    float m = (sact && p < e) ? 1.f : 0.f;
    accL += m * blo(v);
    accH += m * bhi(v);
  }
  // cleanup for deg > 36 (~21% of nodes, mean ~1.5 iterations)
  for (int i = s + 36; i < e; i += 3) {
    int p = i + slot;
    int rb = eidx[min(p, last)];
    unsigned int v = *(const unsigned int*)(base + (unsigned)rb + clsoff);
    float m = (sact && p < e) ? 1.f : 0.f;
    accL += m * blo(v);
    accH += m * bhi(v);
  }
  // reduce the 3 slots down to lanes 0..19 (4 shuffles + 4 adds)
  float bL = __shfl(accL, (lane + 20) & 63, 64);
  float cL = __shfl(accL, (lane + 40) & 63, 64);
  float bH = __shfl(accH, (lane + 20) & 63, 64);
  float cH = __shfl(accH, (lane + 40) & 63, 64);
  accL = accL + bL + cL;                // valid for lanes 0..19
  accH = accH + bH + cH;
  bool act20 = (slot == 0);
  if (FINAL) {
    float2 bb = act20 ? *(const float2*)(bias + 2 * cls) : make_float2(0.f, 0.f);
    float v0 = di * accL + bb.x;
    float v1 = di * accH + bb.y;
    float m = act20 ? fmaxf(v0, v1) : -3.0e38f;
#pragma unroll
    for (int o = 32; o > 0; o >>= 1) m = fmaxf(m, __shfl_xor(m, o, 64));
    float ex = act20 ? (expf(v0 - m) + expf(v1 - m)) : 0.f;
    float ssum = ex;
#pragma unroll
    for (int o = 32; o > 0; o >>= 1) ssum += __shfl_xor(ssum, o, 64);
    float lse = m + logf(ssum);
    if (act20) {
      float2 r = make_float2(v0 - lse, v1 - lse);
      *(float2*)(out + (size_t)node * NC + 2 * cls) = r;
    }
  } else {
    if (act20) {
      float sc = di * di;
      unsigned int pk = (unsigned int)f2bf(sc * accL) |
                        ((unsigned int)f2bf(sc * accH) << 16);
      *(unsigned int*)((char*)gout + (size_t)node * (GST * 2) + clsoff) = pk;
    }
  }
}

extern "C" void kernel_launch(void* const* d_in, const int* in_sizes, int n_in,
                              void* d_out, int out_size, void* d_ws, size_t ws_size,
                              hipStream_t stream) {
  const float* x = (const float*)d_in[0];
  const int* ei  = (const int*)d_in[1];   // [2][E] flat: rows then cols
  const float* W = (const float*)d_in[2];
  const float* b = (const float*)d_in[3];
  // d_in[4] is K; reference fixes K=2 — hardcoded.
  float* out = (float*)d_out;

  const int N = in_sizes[0] / DF;
  const int E = in_sizes[1] / 2;
  const int NB = (N + RSZ - 1) >> RB;     // 391 buckets for N=100K (<= 512)
  const int* row  = ei;
  const int* colv = ei + E;

  char* basep = (char*)d_ws;
  auto alloc = [&](size_t bytes) {
    char* p = basep;
    basep += (bytes + 511) & ~(size_t)511;
    return p;
  };
  int*   cnt    = (int*)  alloc(((size_t)NB) * 4);
  unsigned int* slab = (unsigned int*)alloc((size_t)NB * CAP * 4);  // 19.2 MB
  int*   off    = (int*)  alloc(((size_t)N + 1) * 4);
  int*   eidx   = (int*)  alloc((size_t)E * 4);
  float* dinv   = (float*)alloc((size_t)N * 4);
  unsigned short* g0 = (unsigned short*)alloc((size_t)N * GST * 2);  // 8 MB
  unsigned short* g1 = (unsigned short*)alloc((size_t)N * GST * 2);

  const int gBin = (E + CHUNK - 1) / CHUNK;

  // CSR build: slab binning, then per-bucket finalize (bucket base inline)
  hipMemsetAsync(cnt, 0, (size_t)NB * 4, stream);
  k_binB<<<gBin, 512, 0, stream>>>(row, colv, cnt, slab, E, NB);
  k_binC<<<NB, 512, 0, stream>>>(slab, cnt, off, eidx, dinv, N, NB, E);

  // project 128 -> 40 first (propagation commutes with the linear layer)
  k_xw_scale<<<(N + 127) / 128, 128, 0, stream>>>(x, W, dinv, g0, N);

  // two single-pass hops; hop 2 fuses bias + log_softmax
  const int gHop = (N + 3) / 4;   // 4 waves/block, 1 node/wave
  k_hop<0><<<gHop, 256, 0, stream>>>(off, eidx, dinv, g0, g1, nullptr, nullptr, N);
  k_hop<1><<<gHop, 256, 0, stream>>>(off, eidx, dinv, g1, nullptr, b, out, N);
}

// Round 7
// 322.412 us; speedup vs baseline: 1.3145x; 1.1286x over previous
//
#include <hip/hip_runtime.h>
#include <hip/hip_bf16.h>
#include <math.h>

#define DF 128
#define NC 40
#define GST 40           // g-buffer row stride in ushorts: 80 B rows
#define RB 8             // bucket = node >> 8 (256 nodes/bucket)
#define RSZ 256
#define CHUNK 4096       // edges per binning block
#define CAP 12288        // slab capacity per bucket

__device__ __forceinline__ float bf2f(unsigned short h) {
  unsigned int u = ((unsigned int)h) << 16;
  union { unsigned int u; float f; } c; c.u = u; return c.f;
}
__device__ __forceinline__ unsigned short f2bf(float x) {  // round-to-nearest-even
  union { float f; unsigned int u; } c; c.f = x;
  unsigned int u = c.u;
  return (unsigned short)((u + 0x7fffu + ((u >> 16) & 1u)) >> 16);
}
// unpack a dword holding two packed bf16 (lo = bits 0-15, hi = bits 16-31)
__device__ __forceinline__ float blo(unsigned int u) {
  union { unsigned int u; float f; } c; c.u = u << 16; return c.f;
}
__device__ __forceinline__ float bhi(unsigned int u) {
  union { unsigned int u; float f; } c; c.u = u & 0xffff0000u; return c.f;
}

// ---------- pass B: bin edges into per-bucket slab, count totals ----------
__global__ __launch_bounds__(512) void k_binB(
    const int* __restrict__ row, const int* __restrict__ col,
    int* __restrict__ cnt, unsigned int* __restrict__ slab, int E, int NB) {
  __shared__ int colS[CHUNK];   // 16 KB
  __shared__ int hist[512];
  __shared__ int cursor[512];
  int t = threadIdx.x;
  if (t < NB) hist[t] = 0;
  int s = blockIdx.x * CHUNK, e = min(E, s + CHUNK), n = e - s;
  for (int i = t; i < n; i += 512) colS[i] = col[s + i];
  __syncthreads();
  for (int i = t; i < n; i += 512) atomicAdd(&hist[colS[i] >> RB], 1);
  __syncthreads();
  if (t < NB) cursor[t] = hist[t] ? atomicAdd(&cnt[t], hist[t]) : 0;
  __syncthreads();
  for (int i = t; i < n; i += 512) {
    int c = colS[i];
    int b = c >> RB;
    int p = atomicAdd(&cursor[b], 1);
    slab[(size_t)b * CAP + p] = ((unsigned int)row[s + i] << RB) | (unsigned int)(c & (RSZ - 1));
  }
}

// ---------- pass C: per-bucket CSR finalize + dinv (bucket base computed inline) ----------
// eidx entries are PRE-SCALED to byte offsets (r * 80) for the hop kernels.
__global__ __launch_bounds__(512) void k_binC(
    const unsigned int* __restrict__ slab, const int* __restrict__ cnt,
    int* __restrict__ off, int* __restrict__ eidx, float* __restrict__ dinv,
    int N, int NB, int E) {
  __shared__ int redS[512];
  __shared__ int hist[RSZ];
  __shared__ int sc[RSZ];
  __shared__ int cur[RSZ];
  int b = blockIdx.x;
  int t = threadIdx.x;
  // exclusive prefix of cnt over buckets < b (replaces the single-block scan kernel)
  redS[t] = (t < NB && t < b) ? cnt[t] : 0;
  if (t < RSZ) hist[t] = 0;
  __syncthreads();
  for (int o = 256; o > 0; o >>= 1) {
    if (t < o) redS[t] += redS[t + o];
    __syncthreads();
  }
  int cb = redS[0];
  int cnt_b = cnt[b];
  if (b == 0 && t == 0) off[N] = E;
  const unsigned int* src = slab + (size_t)b * CAP;
  for (int i = t; i < cnt_b; i += 512) atomicAdd(&hist[src[i] & (RSZ - 1)], 1);
  __syncthreads();
  int v = (t < RSZ) ? hist[t] : 0;
  if (t < RSZ) sc[t] = v;
  __syncthreads();
  for (int o = 1; o < RSZ; o <<= 1) {
    int u = (t < RSZ && t >= o) ? sc[t - o] : 0;
    __syncthreads();
    if (t < RSZ) sc[t] += u;
    __syncthreads();
  }
  if (t < RSZ) {
    int pos = cb + sc[t] - v;
    int node = (b << RB) + t;
    if (node < N) {
      off[node] = pos;
      dinv[node] = rsqrtf((float)v + 2.0f);  // degree + 2 self-loops
    }
    cur[t] = pos;
  }
  __syncthreads();
  for (int i = t; i < cnt_b; i += 512) {
    unsigned int en = src[i];
    int p = atomicAdd(&cur[en & (RSZ - 1)], 1);
    eidx[p] = (int)((en >> RB) * (GST * 2u));   // byte offset of source row
  }
}

// ---------- projection: g0[n] = bf16( dinv[n] * (x[n] @ W^T) ), 80 B rows ----------
// Register-blocked 2 nodes/thread: halves per-node LDS W re-reads (the
// measured-structure bottleneck), f32 math and per-class add order unchanged.
__global__ __launch_bounds__(128) void k_xw_scale(
    const float* __restrict__ x, const float* __restrict__ W,
    const float* __restrict__ dinv, unsigned short* __restrict__ g0,
    int N, int NH) {
  __shared__ float4 Ws[NC * (DF / 4)];  // 20 KB
  for (int i = threadIdx.x; i < NC * (DF / 4); i += blockDim.x)
    Ws[i] = ((const float4*)W)[i];
  __syncthreads();
  int t = blockIdx.x * blockDim.x + threadIdx.x;
  if (t >= NH) return;
  int n0 = t;
  int n1 = t + NH;
  bool has1 = n1 < N;
  int n1c = has1 ? n1 : n0;
  float acc0[NC], acc1[NC];
#pragma unroll
  for (int c = 0; c < NC; ++c) { acc0[c] = 0.f; acc1[c] = 0.f; }
  const float4* xr0 = (const float4*)(x + (size_t)n0 * DF);
  const float4* xr1 = (const float4*)(x + (size_t)n1c * DF);
#pragma unroll 1
  for (int ch = 0; ch < 8; ++ch) {
    float4 a0 = xr0[ch * 4 + 0], a1 = xr0[ch * 4 + 1];
    float4 a2 = xr0[ch * 4 + 2], a3 = xr0[ch * 4 + 3];
    float4 b0 = xr1[ch * 4 + 0], b1 = xr1[ch * 4 + 1];
    float4 b2 = xr1[ch * 4 + 2], b3 = xr1[ch * 4 + 3];
#pragma unroll
    for (int c = 0; c < NC; ++c) {
      float4 w0 = Ws[c * (DF / 4) + ch * 4 + 0];
      float4 w1 = Ws[c * (DF / 4) + ch * 4 + 1];
      float4 w2 = Ws[c * (DF / 4) + ch * 4 + 2];
      float4 w3 = Ws[c * (DF / 4) + ch * 4 + 3];
      acc0[c] += (a0.x * w0.x + a0.y * w0.y + a0.z * w0.z + a0.w * w0.w) +
                 (a1.x * w1.x + a1.y * w1.y + a1.z * w1.z + a1.w * w1.w) +
                 (a2.x * w2.x + a2.y * w2.y + a2.z * w2.z + a2.w * w2.w) +
                 (a3.x * w3.x + a3.y * w3.y + a3.z * w3.z + a3.w * w3.w);
      acc1[c] += (b0.x * w0.x + b0.y * w0.y + b0.z * w0.z + b0.w * w0.w) +
                 (b1.x * w1.x + b1.y * w1.y + b1.z * w1.z + b1.w * w1.w) +
                 (b2.x * w2.x + b2.y * w2.y + b2.z * w2.z + b2.w * w2.w) +
                 (b3.x * w3.x + b3.y * w3.y + b3.z * w3.z + b3.w * w3.w);
    }
  }
  float di0 = dinv[n0];
  unsigned int pk[NC / 2];
#pragma unroll
  for (int c2 = 0; c2 < NC / 2; ++c2) {
    unsigned int lo = f2bf(di0 * acc0[c2 * 2 + 0]);
    unsigned int hi = f2bf(di0 * acc0[c2 * 2 + 1]);
    pk[c2] = lo | (hi << 16);
  }
  uint4* gp0 = (uint4*)(g0 + (size_t)n0 * GST);
#pragma unroll
  for (int q = 0; q < 5; ++q)
    gp0[q] = make_uint4(pk[q * 4 + 0], pk[q * 4 + 1], pk[q * 4 + 2], pk[q * 4 + 3]);
  if (has1) {
    float di1 = dinv[n1];
#pragma unroll
    for (int c2 = 0; c2 < NC / 2; ++c2) {
      unsigned int lo = f2bf(di1 * acc1[c2 * 2 + 0]);
      unsigned int hi = f2bf(di1 * acc1[c2 * 2 + 1]);
      pk[c2] = lo | (hi << 16);
    }
    uint4* gp1 = (uint4*)(g0 + (size_t)n1 * GST);
#pragma unroll
    for (int q = 0; q < 5; ++q)
      gp1[q] = make_uint4(pk[q * 4 + 0], pk[q * 4 + 1], pk[q * 4 + 2], pk[q * 4 + 3]);
  }
}

// ---------- hop kernel: scalar-indexed, 3 edges per gather instruction ----------
// One wave = one node. eidx reads are WAVE-UNIFORM (scalar pipe, free); each
// gather instruction covers 3 edges' 80 B rows via cndmask-selected scalar
// byte offsets + 20 class-lanes x uint (2 bf16). Main loop: unmasked 24-edge
// blocks (8 gathers in flight; lanes 60-63 accumulate into dead regs). Tail:
// one masked clamped 24-edge shot. FINAL fuses bias + log_softmax.
#define EDGE3U(Q0, Q1, Q2)                                                \
  {                                                                       \
    int sel_ = (slot == 0) ? (Q0) : (slot == 1) ? (Q1) : (Q2);            \
    unsigned v_ = *(const unsigned*)(base + (unsigned)(sel_ + clsoff));   \
    accL += blo(v_); accH += bhi(v_);                                     \
  }
#define EDGE3M(Q0, Q1, Q2, PB)                                            \
  {                                                                       \
    int sel_ = (slot == 0) ? (Q0) : (slot == 1) ? (Q1) : (Q2);            \
    unsigned v_ = *(const unsigned*)(base + (unsigned)(sel_ + clsoff));   \
    float m_ = (sact && (PB) + slot < e) ? 1.f : 0.f;                     \
    accL += m_ * blo(v_); accH += m_ * bhi(v_);                           \
  }

template<int FINAL>
__global__ __launch_bounds__(256) void k_hop(
    const int* __restrict__ off, const int* __restrict__ eidx,
    const float* __restrict__ dinv, const unsigned short* __restrict__ gin,
    unsigned short* __restrict__ gout, const float* __restrict__ bias,
    float* __restrict__ out, int N) {
  int wv = threadIdx.x >> 6;
  int lane = threadIdx.x & 63;
  int node = blockIdx.x * 4 + wv;
  if (node >= N) return;
  int slot = lane / 20;                 // 0..2 edge slots; lanes 60-63 -> dead slot 3
  int cls = lane - slot * 20;           // class-pair index 0..19
  bool sact = slot < 3;
  int s = __builtin_amdgcn_readfirstlane(off[node]);
  int e = __builtin_amdgcn_readfirstlane(off[node + 1]);
  float di = dinv[node];
  const char* base = (const char*)gin;
  int clsoff = cls * 4;
  float accL, accH;
  {                                     // double self-loop (own row, 2 classes/lane)
    unsigned int v = *(const unsigned int*)(base + (size_t)node * (GST * 2) + clsoff);
    bool s0 = (slot == 0);
    accL = s0 ? 2.f * blo(v) : 0.f;
    accH = s0 ? 2.f * bhi(v) : 0.f;
  }
  int i = s;
  for (; i + 24 <= e; i += 24) {        // unmasked: 8 gathers in flight
    int b0  = eidx[i + 0],  b1  = eidx[i + 1],  b2  = eidx[i + 2];
    int b3  = eidx[i + 3],  b4  = eidx[i + 4],  b5  = eidx[i + 5];
    int b6  = eidx[i + 6],  b7  = eidx[i + 7],  b8  = eidx[i + 8];
    int b9  = eidx[i + 9],  b10 = eidx[i + 10], b11 = eidx[i + 11];
    int b12 = eidx[i + 12], b13 = eidx[i + 13], b14 = eidx[i + 14];
    int b15 = eidx[i + 15], b16 = eidx[i + 16], b17 = eidx[i + 17];
    int b18 = eidx[i + 18], b19 = eidx[i + 19], b20 = eidx[i + 20];
    int b21 = eidx[i + 21], b22 = eidx[i + 22], b23 = eidx[i + 23];
    EDGE3U(b0, b1, b2)    EDGE3U(b3, b4, b5)
    EDGE3U(b6, b7, b8)    EDGE3U(b9, b10, b11)
    EDGE3U(b12, b13, b14) EDGE3U(b15, b16, b17)
    EDGE3U(b18, b19, b20) EDGE3U(b21, b22, b23)
  }
  if (i < e) {                          // masked clamped shot covers tail (<= 23 edges)
    int last = e - 1;
    int q0  = eidx[min(i + 0,  last)], q1  = eidx[min(i + 1,  last)], q2  = eidx[min(i + 2,  last)];
    int q3  = eidx[min(i + 3,  last)], q4  = eidx[min(i + 4,  last)], q5  = eidx[min(i + 5,  last)];
    int q6  = eidx[min(i + 6,  last)], q7  = eidx[min(i + 7,  last)], q8  = eidx[min(i + 8,  last)];
    int q9  = eidx[min(i + 9,  last)], q10 = eidx[min(i + 10, last)], q11 = eidx[min(i + 11, last)];
    int q12 = eidx[min(i + 12, last)], q13 = eidx[min(i + 13, last)], q14 = eidx[min(i + 14, last)];
    int q15 = eidx[min(i + 15, last)], q16 = eidx[min(i + 16, last)], q17 = eidx[min(i + 17, last)];
    int q18 = eidx[min(i + 18, last)], q19 = eidx[min(i + 19, last)], q20 = eidx[min(i + 20, last)];
    int q21 = eidx[min(i + 21, last)], q22 = eidx[min(i + 22, last)], q23 = eidx[min(i + 23, last)];
    EDGE3M(q0, q1, q2, i + 0)     EDGE3M(q3, q4, q5, i + 3)
    EDGE3M(q6, q7, q8, i + 6)     EDGE3M(q9, q10, q11, i + 9)
    EDGE3M(q12, q13, q14, i + 12) EDGE3M(q15, q16, q17, i + 15)
    EDGE3M(q18, q19, q20, i + 18) EDGE3M(q21, q22, q23, i + 21)
  }
  // reduce the 3 slots down to lanes 0..19 (4 shuffles + adds)
  float bL = __shfl(accL, (lane + 20) & 63, 64);
  float cL = __shfl(accL, (lane + 40) & 63, 64);
  float bH = __shfl(accH, (lane + 20) & 63, 64);
  float cH = __shfl(accH, (lane + 40) & 63, 64);
  accL = accL + bL + cL;                // valid for lanes 0..19
  accH = accH + bH + cH;
  bool act20 = (slot == 0);
  if (FINAL) {
    float2 bb = act20 ? *(const float2*)(bias + 2 * cls) : make_float2(0.f, 0.f);
    float v0 = di * accL + bb.x;
    float v1 = di * accH + bb.y;
    float m = act20 ? fmaxf(v0, v1) : -3.0e38f;
#pragma unroll
    for (int o = 32; o > 0; o >>= 1) m = fmaxf(m, __shfl_xor(m, o, 64));
    float ex = act20 ? (expf(v0 - m) + expf(v1 - m)) : 0.f;
    float ssum = ex;
#pragma unroll
    for (int o = 32; o > 0; o >>= 1) ssum += __shfl_xor(ssum, o, 64);
    float lse = m + logf(ssum);
    if (act20) {
      float2 r = make_float2(v0 - lse, v1 - lse);
      *(float2*)(out + (size_t)node * NC + 2 * cls) = r;
    }
  } else {
    if (act20) {
      float sc = di * di;
      unsigned int pk = (unsigned int)f2bf(sc * accL) |
                        ((unsigned int)f2bf(sc * accH) << 16);
      *(unsigned int*)((char*)gout + (size_t)node * (GST * 2) + clsoff) = pk;
    }
  }
}

extern "C" void kernel_launch(void* const* d_in, const int* in_sizes, int n_in,
                              void* d_out, int out_size, void* d_ws, size_t ws_size,
                              hipStream_t stream) {
  const float* x = (const float*)d_in[0];
  const int* ei  = (const int*)d_in[1];   // [2][E] flat: rows then cols
  const float* W = (const float*)d_in[2];
  const float* b = (const float*)d_in[3];
  // d_in[4] is K; reference fixes K=2 — hardcoded.
  float* out = (float*)d_out;

  const int N = in_sizes[0] / DF;
  const int E = in_sizes[1] / 2;
  const int NB = (N + RSZ - 1) >> RB;     // 391 buckets for N=100K (<= 512)
  const int* row  = ei;
  const int* colv = ei + E;

  char* basep = (char*)d_ws;
  auto alloc = [&](size_t bytes) {
    char* p = basep;
    basep += (bytes + 511) & ~(size_t)511;
    return p;
  };
  int*   cnt    = (int*)  alloc(((size_t)NB) * 4);
  unsigned int* slab = (unsigned int*)alloc((size_t)NB * CAP * 4);  // 19.2 MB
  int*   off    = (int*)  alloc(((size_t)N + 1) * 4);
  int*   eidx   = (int*)  alloc((size_t)E * 4);
  float* dinv   = (float*)alloc((size_t)N * 4);
  unsigned short* g0 = (unsigned short*)alloc((size_t)N * GST * 2);  // 8 MB
  unsigned short* g1 = (unsigned short*)alloc((size_t)N * GST * 2);

  const int gBin = (E + CHUNK - 1) / CHUNK;

  // CSR build: slab binning, then per-bucket finalize (bucket base inline)
  hipMemsetAsync(cnt, 0, (size_t)NB * 4, stream);
  k_binB<<<gBin, 512, 0, stream>>>(row, colv, cnt, slab, E, NB);
  k_binC<<<NB, 512, 0, stream>>>(slab, cnt, off, eidx, dinv, N, NB, E);

  // project 128 -> 40 first (propagation commutes with the linear layer)
  const int NH = (N + 1) / 2;
  k_xw_scale<<<(NH + 127) / 128, 128, 0, stream>>>(x, W, dinv, g0, N, NH);

  // two single-pass hops; hop 2 fuses bias + log_softmax
  const int gHop = (N + 3) / 4;   // 4 waves/block, 1 node/wave
  k_hop<0><<<gHop, 256, 0, stream>>>(off, eidx, dinv, g0, g1, nullptr, nullptr, N);
  k_hop<1><<<gHop, 256, 0, stream>>>(off, eidx, dinv, g1, nullptr, b, out, N);
}